// Round 11
// baseline (319.468 us; speedup 1.0000x reference)
//
#include <hip/hip_runtime.h>
#include <hip/hip_bf16.h>

// ---------------------------------------------------------------------------
// InductiveBundleMapLearner: 2x SAGEConv (mean) -> linear -> Cayley map
// bf16 MFMA pipeline. Proven single-buffered GEMM + XCD swizzle.
// NEW: channel-sliced aggregation (32-ch slices -> 3.2MB gather target fits
// per-XCD L2) and fused prep kernel (cast || hist || build_wcat).
// ---------------------------------------------------------------------------

#define WS_ALIGN(x) (((x) + 255) & ~size_t(255))

typedef __attribute__((ext_vector_type(8))) short short8;
typedef __attribute__((ext_vector_type(4))) float floatx4;

static __device__ __forceinline__ ushort f2b(float f) {
    unsigned u = __builtin_bit_cast(unsigned, f);
    u = (u + 0x7fffu + ((u >> 16) & 1u)) >> 16;   // RNE, finite inputs
    return (ushort)u;
}
static __device__ __forceinline__ float b2f(ushort h) {
    unsigned u = ((unsigned)h) << 16;
    return __builtin_bit_cast(float, u);
}

// ---------------- fused prep: cast || hist || build_wcat ----------------
// blocks [0, cb): fp32->bf16 cast of x (grid-stride) -- dispatched first
// blocks [cb, cb+eb): degree histogram
// blocks [cb+eb, ...): weight concat+cast

__global__ __launch_bounds__(256)
void prep_kernel(const float* __restrict__ x, ushort* __restrict__ xb, int n8, int cb,
                 const int* __restrict__ dst, int* __restrict__ deg, int E, int eb,
                 const float* __restrict__ W1l, const float* __restrict__ W1r,
                 const float* __restrict__ W2l, const float* __restrict__ W2r,
                 ushort* __restrict__ Wc1, ushort* __restrict__ Wc2) {
    const int b = blockIdx.x;
    const int tid = threadIdx.x;
    if (b < cb) {
        for (int i = b * 256 + tid; i < n8; i += cb * 256) {
            const float4* s4 = reinterpret_cast<const float4*>(x + (size_t)i * 8);
            float4 v0 = s4[0], v1 = s4[1];
            short8 o;
            o[0] = (short)f2b(v0.x); o[1] = (short)f2b(v0.y);
            o[2] = (short)f2b(v0.z); o[3] = (short)f2b(v0.w);
            o[4] = (short)f2b(v1.x); o[5] = (short)f2b(v1.y);
            o[6] = (short)f2b(v1.z); o[7] = (short)f2b(v1.w);
            *reinterpret_cast<short8*>(xb + (size_t)i * 8) = o;
        }
    } else if (b < cb + eb) {
        int e = (b - cb) * 256 + tid;
        if (e < E) atomicAdd(&deg[dst[e]], 1);
    } else {
        int idx = (b - cb - eb) * 256 + tid;
        const int n1 = (512 * 512) / 8;
        const int n2 = (256 * 256) / 8;
        const float* src;
        ushort* dstp;
        if (idx < n1) {
            int e = idx * 8;
            int row = e >> 9, col = e & 511;
            src = (row < 256) ? &W1l[row * 512 + col] : &W1r[(row - 256) * 512 + col];
            dstp = &Wc1[e];
        } else if (idx < n1 + n2) {
            int e = (idx - n1) * 8;
            int row = e >> 8, col = e & 255;
            src = (row < 128) ? &W2l[row * 256 + col] : &W2r[(row - 128) * 256 + col];
            dstp = &Wc2[e];
        } else {
            return;
        }
        const float4* s4 = reinterpret_cast<const float4*>(src);
        float4 v0 = s4[0], v1 = s4[1];
        short8 o;
        o[0] = (short)f2b(v0.x); o[1] = (short)f2b(v0.y);
        o[2] = (short)f2b(v0.z); o[3] = (short)f2b(v0.w);
        o[4] = (short)f2b(v1.x); o[5] = (short)f2b(v1.y);
        o[6] = (short)f2b(v1.z); o[7] = (short)f2b(v1.w);
        *reinterpret_cast<short8*>(dstp) = o;
    }
}

// ---------------- scan (3-phase) ----------------

__global__ __launch_bounds__(256)
void scan_phase1(const int* __restrict__ deg, int* __restrict__ bsum, int n) {
    __shared__ int red[256];
    const int t = threadIdx.x;
    const int i = blockIdx.x * 1024 + t * 4;
    int s = 0;
    if (i + 4 <= n) {
        int4 v = *reinterpret_cast<const int4*>(&deg[i]);
        s = v.x + v.y + v.z + v.w;
    } else {
        for (int k = i; k < n; ++k) s += deg[k];
    }
    red[t] = s;
    __syncthreads();
#pragma unroll
    for (int off = 128; off > 0; off >>= 1) {
        if (t < off) red[t] += red[t + off];
        __syncthreads();
    }
    if (t == 0) bsum[blockIdx.x] = red[0];
}

__global__ __launch_bounds__(256)
void scan_phase2(int* __restrict__ bsum, int* __restrict__ rowptr, int nb, int n) {
    __shared__ int sh[256];
    const int t = threadIdx.x;
    int orig = (t < nb) ? bsum[t] : 0;
    sh[t] = orig;
    __syncthreads();
#pragma unroll
    for (int off = 1; off < 256; off <<= 1) {
        int v = (t >= off) ? sh[t - off] : 0;
        __syncthreads();
        sh[t] += v;
        __syncthreads();
    }
    if (t < nb) bsum[t] = sh[t] - orig;          // exclusive block offsets
    if (t == 255) rowptr[n] = sh[255];           // total
}

__global__ __launch_bounds__(256)
void scan_phase3(const int* __restrict__ deg, const int* __restrict__ bsum,
                 int* __restrict__ rowptr, int n) {
    __shared__ int red[256];
    const int t = threadIdx.x;
    const int i = blockIdx.x * 1024 + t * 4;
    int v0 = 0, v1 = 0, v2 = 0, v3 = 0;
    if (i + 4 <= n) {
        int4 v = *reinterpret_cast<const int4*>(&deg[i]);
        v0 = v.x; v1 = v.y; v2 = v.z; v3 = v.w;
    } else {
        if (i     < n) v0 = deg[i];
        if (i + 1 < n) v1 = deg[i + 1];
        if (i + 2 < n) v2 = deg[i + 2];
        if (i + 3 < n) v3 = deg[i + 3];
    }
    int s = v0 + v1 + v2 + v3;
    red[t] = s;
    __syncthreads();
#pragma unroll
    for (int off = 1; off < 256; off <<= 1) {
        int u = (t >= off) ? red[t - off] : 0;
        __syncthreads();
        red[t] += u;
        __syncthreads();
    }
    int pre = bsum[blockIdx.x] + red[t] - s;
    if (i + 4 <= n) {
        int4 o;
        o.x = pre; o.y = pre + v0; o.z = pre + v0 + v1; o.w = pre + v0 + v1 + v2;
        *reinterpret_cast<int4*>(&rowptr[i]) = o;
    } else {
        if (i     < n) rowptr[i]     = pre;
        if (i + 1 < n) rowptr[i + 1] = pre + v0;
        if (i + 2 < n) rowptr[i + 2] = pre + v0 + v1;
        if (i + 3 < n) rowptr[i + 3] = pre + v0 + v1 + v2;
    }
}

__global__ void scatter_kernel(const int* __restrict__ src, const int* __restrict__ dst,
                               const int* __restrict__ rowptr, int* __restrict__ cursor,
                               int* __restrict__ adj, int E) {
    int e = blockIdx.x * blockDim.x + threadIdx.x;
    if (e < E) {
        int d = dst[e];
        int p = atomicAdd(&cursor[d], 1);
        adj[rowptr[d] + p] = src[e];
    }
}

// ---------------- bf16 MFMA GEMM (proven): [Cl|Cr] = A @ B^T ----------
// 128x128 tile, BK=64, 256 threads (4 waves of 64x64), 16x16x32 MFMA.
// Single-buffered LDS, global_load_lds both operands, XCD-bijective swizzle.
// LDS granule (row, g) at byte row*128 + ((g*16) ^ ((row&7)<<4)).

__global__ __launch_bounds__(256)
void gemm_bf16(const ushort* __restrict__ A, const ushort* __restrict__ B,
               ushort* __restrict__ Cl, ushort* __restrict__ Cr,
               int M, int K, int S, int gx) {
    __shared__ ushort As[128 * 64];   // 16 KB
    __shared__ ushort Bs[128 * 64];   // 16 KB
    const int tid  = threadIdx.x;
    const int wave = tid >> 6;
    const int lane = tid & 63;

    // bijective XCD-contiguous swizzle (m204)
    const int W = gridDim.x;
    const int q = W >> 3, r = W & 7;
    const int xcd = blockIdx.x & 7, slot = blockIdx.x >> 3;
    const int w = (xcd < r ? xcd * (q + 1) : r * (q + 1) + (xcd - r) * q) + slot;
    const int row0 = (w / gx) * 128;
    const int col0 = (w % gx) * 128;

    const int wm = (wave & 1) * 64;
    const int wn = (wave >> 1) * 64;

    floatx4 acc[4][4];
#pragma unroll
    for (int i = 0; i < 4; ++i)
#pragma unroll
        for (int j = 0; j < 4; ++j)
            acc[i][j] = (floatx4){0.f, 0.f, 0.f, 0.f};

    const int rsub = lane >> 3;                        // row within 8-row chunk
    const int ksw  = ((lane & 7) * 16) ^ (rsub << 4);  // pre-swizzled byte-in-row

    for (int k0 = 0; k0 < K; k0 += 64) {
#pragma unroll
        for (int i = 0; i < 4; ++i) {
            int chunk = wave * 4 + i;
            int rr = chunk * 8 + rsub;
            int grow = row0 + rr;
            if (grow >= M) grow = M - 1;               // clamp (stores guarded)
            const char* srcp = (const char*)(A + (size_t)grow * K + k0) + ksw;
            __builtin_amdgcn_global_load_lds(
                (const __attribute__((address_space(1))) unsigned int*)srcp,
                (__attribute__((address_space(3))) unsigned int*)(&As[chunk * 512]),
                16, 0, 0);
        }
#pragma unroll
        for (int i = 0; i < 4; ++i) {
            int chunk = wave * 4 + i;
            int rr = chunk * 8 + rsub;
            int gcol = col0 + rr;
            const char* srcp = (const char*)(B + (size_t)gcol * K + k0) + ksw;
            __builtin_amdgcn_global_load_lds(
                (const __attribute__((address_space(1))) unsigned int*)srcp,
                (__attribute__((address_space(3))) unsigned int*)(&Bs[chunk * 512]),
                16, 0, 0);
        }
        __syncthreads();

#pragma unroll
        for (int kk = 0; kk < 2; ++kk) {
            short8 af[4], bf[4];
            const int kb = (kk * 64 + ((lane >> 4) << 4)) ^ ((lane & 7) << 4);
#pragma unroll
            for (int im = 0; im < 4; ++im) {
                int rr = wm + im * 16 + (lane & 15);
                af[im] = *reinterpret_cast<const short8*>((const char*)As + rr * 128 + kb);
            }
#pragma unroll
            for (int in = 0; in < 4; ++in) {
                int rr = wn + in * 16 + (lane & 15);
                bf[in] = *reinterpret_cast<const short8*>((const char*)Bs + rr * 128 + kb);
            }
#pragma unroll
            for (int im = 0; im < 4; ++im)
#pragma unroll
                for (int in = 0; in < 4; ++in)
                    acc[im][in] = __builtin_amdgcn_mfma_f32_16x16x32_bf16(
                        af[im], bf[in], acc[im][in], 0, 0, 0);
        }
        __syncthreads();
    }

    // epilogue: C/D layout col=lane&15, row=(lane>>4)*4+reg (m89-verified)
    ushort* Cbase = (col0 < S) ? Cl : Cr;
    const int cb = (col0 < S) ? col0 : col0 - S;
#pragma unroll
    for (int im = 0; im < 4; ++im) {
#pragma unroll
        for (int reg = 0; reg < 4; ++reg) {
            int rr = row0 + wm + im * 16 + ((lane >> 4) << 2) + reg;
            if (rr < M) {
                size_t base = (size_t)rr * S + cb + wn + (lane & 15);
#pragma unroll
                for (int in = 0; in < 4; ++in)
                    Cbase[base + in * 16] = f2b(acc[im][in][reg]);
            }
        }
    }
}

// ---------------- channel-sliced aggregation ----------------
// h = relu(mean_l + self_r + b). blockIdx.y = 32-channel slice; the active
// gather target (Yl[:, slice]) is 3.2MB -> fits each XCD's 4MB L2; blockIdx.x
// varies fastest so all CUs process the same slice concurrently.
// 8 lanes/node, 4 ch/lane (ushort4), 8 edges in flight.

template <int F>
__global__ __launch_bounds__(256)
void agg_sliced(const ushort* __restrict__ Yl, const ushort* __restrict__ Yr,
                const float* __restrict__ bias,
                const int* __restrict__ rowptr, const int* __restrict__ adj,
                ushort* __restrict__ H, int n) {
    const int g   = threadIdx.x >> 3;          // node group 0..31
    const int sub = threadIdx.x & 7;
    const int node = blockIdx.x * 32 + g;
    if (node >= n) return;
    const int c = blockIdx.y * 32 + sub * 4;
    const int start = rowptr[node], end = rowptr[node + 1];

    float a0 = 0.f, a1 = 0.f, a2 = 0.f, a3 = 0.f;
    int e = start;
    for (; e + 8 <= end; e += 8) {
        ushort4 rr[8];
#pragma unroll
        for (int u = 0; u < 8; ++u) {
            int s = adj[e + u];
            rr[u] = *reinterpret_cast<const ushort4*>(&Yl[(size_t)s * F + c]);
        }
#pragma unroll
        for (int u = 0; u < 8; ++u) {
            a0 += b2f(rr[u].x); a1 += b2f(rr[u].y);
            a2 += b2f(rr[u].z); a3 += b2f(rr[u].w);
        }
    }
    for (; e < end; ++e) {
        int s = adj[e];
        ushort4 rr = *reinterpret_cast<const ushort4*>(&Yl[(size_t)s * F + c]);
        a0 += b2f(rr.x); a1 += b2f(rr.y); a2 += b2f(rr.z); a3 += b2f(rr.w);
    }

    const int d = end - start;
    const float inv = 1.0f / (float)(d > 0 ? d : 1);
    ushort4 sv = *reinterpret_cast<const ushort4*>(&Yr[(size_t)node * F + c]);
    float4 bv = *reinterpret_cast<const float4*>(&bias[c]);
    ushort4 o;
    o.x = f2b(fmaxf(a0 * inv + b2f(sv.x) + bv.x, 0.f));
    o.y = f2b(fmaxf(a1 * inv + b2f(sv.y) + bv.y, 0.f));
    o.z = f2b(fmaxf(a2 * inv + b2f(sv.z) + bv.z, 0.f));
    o.w = f2b(fmaxf(a3 * inv + b2f(sv.w) + bv.w, 0.f));
    *reinterpret_cast<ushort4*>(&H[(size_t)node * F + c]) = o;
}

// ---------------- params: p = h2 @ Wp^T + bp -> P[N,32] ----------------
// 8 lanes/node; lane l owns params {l, l+8, l+16, l+24}; pitch-132 LDS.

__global__ __launch_bounds__(256)
void params_kernel(const ushort* __restrict__ H2, const float* __restrict__ Wp,
                   const float* __restrict__ bp, float* __restrict__ P, int n) {
    __shared__ float WpS[32 * 132];
    __shared__ float bpS[32];
    for (int t = threadIdx.x; t < 32 * 132; t += 256) WpS[t] = 0.f;
    if (threadIdx.x < 32) bpS[threadIdx.x] = (threadIdx.x < 28) ? bp[threadIdx.x] : 0.f;
    __syncthreads();
    for (int t = threadIdx.x; t < 28 * 128; t += 256) {
        int r = t >> 7, c = t & 127;
        WpS[r * 132 + c] = Wp[t];
    }
    __syncthreads();

    const int node = blockIdx.x * 32 + (threadIdx.x >> 3);
    const int l = threadIdx.x & 7;
    if (node >= n) return;

    short8 h8[16];
    const short8* hp = reinterpret_cast<const short8*>(&H2[(size_t)node * 128]);
#pragma unroll
    for (int q = 0; q < 16; ++q) h8[q] = hp[q];

    float acc0 = bpS[l], acc1 = bpS[l + 8], acc2 = bpS[l + 16], acc3 = bpS[l + 24];
#pragma unroll
    for (int q = 0; q < 32; ++q) {
        float h0 = b2f((ushort)h8[q >> 1][(q & 1) * 4 + 0]);
        float h1 = b2f((ushort)h8[q >> 1][(q & 1) * 4 + 1]);
        float h2 = b2f((ushort)h8[q >> 1][(q & 1) * 4 + 2]);
        float h3 = b2f((ushort)h8[q >> 1][(q & 1) * 4 + 3]);
        float4 w0 = *reinterpret_cast<const float4*>(&WpS[(l +  0) * 132 + 4 * q]);
        float4 w1 = *reinterpret_cast<const float4*>(&WpS[(l +  8) * 132 + 4 * q]);
        float4 w2 = *reinterpret_cast<const float4*>(&WpS[(l + 16) * 132 + 4 * q]);
        float4 w3 = *reinterpret_cast<const float4*>(&WpS[(l + 24) * 132 + 4 * q]);
        acc0 += h0 * w0.x + h1 * w0.y + h2 * w0.z + h3 * w0.w;
        acc1 += h0 * w1.x + h1 * w1.y + h2 * w1.z + h3 * w1.w;
        acc2 += h0 * w2.x + h1 * w2.y + h2 * w2.z + h3 * w2.w;
        acc3 += h0 * w3.x + h1 * w3.y + h2 * w3.z + h3 * w3.w;
    }
    float* pout = &P[(size_t)node * 32];
    pout[l]      = acc0;
    pout[l + 8]  = acc1;
    pout[l + 16] = acc2;
    pout[l + 24] = acc3;
}

// ---------------- Cayley: O = (I-A)^{-1}(I+A) ----------------

__global__ __launch_bounds__(256)
void cayley_kernel(const float* __restrict__ P, float* __restrict__ Out, int n) {
    int i = blockIdx.x * blockDim.x + threadIdx.x;
    if (i >= n) return;
    float p[28];
    const float4* pp = reinterpret_cast<const float4*>(&P[(size_t)i * 32]);
#pragma unroll
    for (int q = 0; q < 7; ++q) {
        float4 v = pp[q];
        p[4 * q + 0] = v.x; p[4 * q + 1] = v.y;
        p[4 * q + 2] = v.z; p[4 * q + 3] = v.w;
    }

    float M_[8][8], B_[8][8];
#pragma unroll
    for (int r = 0; r < 8; ++r)
#pragma unroll
        for (int c = 0; c < 8; ++c) {
            M_[r][c] = (r == c) ? 1.f : 0.f;
            B_[r][c] = (r == c) ? 1.f : 0.f;
        }
    {
        int idx = 0;
#pragma unroll
        for (int r = 0; r < 8; ++r)
#pragma unroll
            for (int c = r + 1; c < 8; ++c) {
                float a = p[idx++];
                M_[r][c] -= a;  M_[c][r] += a;
                B_[r][c] += a;  B_[c][r] -= a;
            }
    }
#pragma unroll
    for (int col = 0; col < 8; ++col) {
        float inv = 1.0f / M_[col][col];
#pragma unroll
        for (int c = 0; c < 8; ++c) { M_[col][c] *= inv; B_[col][c] *= inv; }
#pragma unroll
        for (int r = 0; r < 8; ++r) {
            if (r == col) continue;
            float f = M_[r][col];
#pragma unroll
            for (int c = 0; c < 8; ++c) {
                M_[r][c] -= f * M_[col][c];
                B_[r][c] -= f * B_[col][c];
            }
        }
    }
    float* out = &Out[(size_t)i * 64];
#pragma unroll
    for (int r = 0; r < 8; ++r) {
        float4 o0 = make_float4(B_[r][0], B_[r][1], B_[r][2], B_[r][3]);
        float4 o1 = make_float4(B_[r][4], B_[r][5], B_[r][6], B_[r][7]);
        *reinterpret_cast<float4*>(&out[r * 8 + 0]) = o0;
        *reinterpret_cast<float4*>(&out[r * 8 + 4]) = o1;
    }
}

// ---------------------------------------------------------------------------

extern "C" void kernel_launch(void* const* d_in, const int* in_sizes, int n_in,
                              void* d_out, int out_size, void* d_ws, size_t ws_size,
                              hipStream_t stream) {
    const float* x   = (const float*)d_in[0];
    const int*   ei  = (const int*)d_in[1];
    const float* W1l = (const float*)d_in[2];
    const float* b1  = (const float*)d_in[3];
    const float* W1r = (const float*)d_in[4];
    const float* W2l = (const float*)d_in[5];
    const float* b2  = (const float*)d_in[6];
    const float* W2r = (const float*)d_in[7];
    const float* Wp  = (const float*)d_in[8];
    const float* bp  = (const float*)d_in[9];
    float* out = (float*)d_out;

    const int IN_DIM = 512;
    const int N = in_sizes[0] / IN_DIM;   // 50000
    const int E = in_sizes[1] / 2;        // 800000

    char* ws = (char*)d_ws;
    size_t off = 0;
    int* deg      = (int*)(ws + off); off = WS_ALIGN(off + (size_t)N * 4);
    int* rowptr   = (int*)(ws + off); off = WS_ALIGN(off + (size_t)(N + 1) * 4);
    int* cursor   = (int*)(ws + off); off = WS_ALIGN(off + (size_t)N * 4);
    int* bsum     = (int*)(ws + off); off = WS_ALIGN(off + (size_t)256 * 4);
    int* adj      = (int*)(ws + off); off = WS_ALIGN(off + (size_t)E * 4);
    ushort* xb    = (ushort*)(ws + off); off = WS_ALIGN(off + (size_t)N * 512 * 2);
    ushort* Yl    = (ushort*)(ws + off); off = WS_ALIGN(off + (size_t)N * 256 * 2);
    ushort* Yr    = (ushort*)(ws + off); off = WS_ALIGN(off + (size_t)N * 256 * 2);
    ushort* h1    = (ushort*)(ws + off); off = WS_ALIGN(off + (size_t)N * 256 * 2);
    ushort* zl    = (ushort*)(ws + off); off = WS_ALIGN(off + (size_t)N * 128 * 2);
    ushort* zr    = (ushort*)(ws + off); off = WS_ALIGN(off + (size_t)N * 128 * 2);
    ushort* Wc1   = (ushort*)(ws + off); off = WS_ALIGN(off + (size_t)512 * 512 * 2);
    ushort* Wc2   = (ushort*)(ws + off); off = WS_ALIGN(off + (size_t)256 * 256 * 2);
    float*  Pp    = (float*)(ws + off);  off = WS_ALIGN(off + (size_t)N * 32 * 4);

    const int* src = ei;
    const int* dst = ei + E;

    hipMemsetAsync(deg, 0, (size_t)N * 4, stream);
    hipMemsetAsync(cursor, 0, (size_t)N * 4, stream);

    const int eb = (E + 255) / 256;       // 3125 hist blocks
    const int cb = 1024;                  // cast blocks (grid-stride)
    const int wb = ((512 * 512 + 256 * 256) / 8 + 255) / 256;
    const int nb = (N + 1023) / 1024;     // <= 256

    prep_kernel<<<cb + eb + wb, 256, 0, stream>>>(
        x, xb, N * 512 / 8, cb, dst, deg, E, eb,
        W1l, W1r, W2l, W2r, Wc1, Wc2);
    scan_phase1<<<nb, 256, 0, stream>>>(deg, bsum, N);
    scan_phase2<<<1, 256, 0, stream>>>(bsum, rowptr, nb, N);
    scan_phase3<<<nb, 256, 0, stream>>>(deg, bsum, rowptr, N);
    scatter_kernel<<<eb, 256, 0, stream>>>(src, dst, rowptr, cursor, adj, E);

    int gm = (N + 127) / 128;   // 391
    int ab = (N + 31) / 32;     // 1563

    // layer 1: [Yl|Yr] = xb @ Wc1^T   ([N,256] each, bf16)
    gemm_bf16<<<gm * 4, 256, 0, stream>>>(xb, Wc1, Yl, Yr, N, 512, 256, 4);
    // h1 = relu(mean + self + b1)  [N,256] bf16, 8 x 32-ch slices
    agg_sliced<256><<<dim3(ab, 8), 256, 0, stream>>>(Yl, Yr, b1, rowptr, adj, h1, N);

    // layer 2: [zl|zr] = h1 @ Wc2^T   ([N,128] each)
    gemm_bf16<<<gm * 2, 256, 0, stream>>>(h1, Wc2, zl, zr, N, 256, 128, 2);
    // h2  [N,128] bf16 (reuse Yl), 4 x 32-ch slices
    ushort* h2 = Yl;
    agg_sliced<128><<<dim3(ab, 4), 256, 0, stream>>>(zl, zr, b2, rowptr, adj, h2, N);

    // params p = h2 @ Wp^T + bp -> P [N,32] fp32 (8 lanes/node)
    params_kernel<<<(N + 31) / 32, 256, 0, stream>>>(h2, Wp, bp, Pp, N);
    // Cayley -> out [N,8,8] fp32
    cayley_kernel<<<(N + 255) / 256, 256, 0, stream>>>(Pp, out, N);
}

// Round 12
// 305.047 us; speedup vs baseline: 1.0473x; 1.0473x over previous
//
#include <hip/hip_runtime.h>
#include <hip/hip_bf16.h>

// ---------------------------------------------------------------------------
// InductiveBundleMapLearner: 2x SAGEConv (mean) -> linear -> Cayley map
// R7-proven core (fused-cast 512-thread gemm_wide, 16B 4-deep gather agg)
// + fused agg2+params (h2 never materialized) + fused prep (hist||wcat).
// ---------------------------------------------------------------------------

#define WS_ALIGN(x) (((x) + 255) & ~size_t(255))

typedef __attribute__((ext_vector_type(8))) short short8;
typedef __attribute__((ext_vector_type(4))) float floatx4;

static __device__ __forceinline__ ushort f2b(float f) {
    unsigned u = __builtin_bit_cast(unsigned, f);
    u = (u + 0x7fffu + ((u >> 16) & 1u)) >> 16;   // RNE, finite inputs
    return (ushort)u;
}
static __device__ __forceinline__ float b2f(ushort h) {
    unsigned u = ((unsigned)h) << 16;
    return __builtin_bit_cast(float, u);
}
static __device__ __forceinline__ unsigned pk2(float a, float b) {
    return (unsigned)f2b(a) | ((unsigned)f2b(b) << 16);
}

// ---------------- fused prep: hist || build_wcat ----------------
// blocks [0, eb): degree histogram; blocks [eb, eb+wb): weight concat+cast.

__global__ __launch_bounds__(256)
void prep_kernel(const int* __restrict__ dst, int* __restrict__ deg, int E, int eb,
                 const float* __restrict__ W1l, const float* __restrict__ W1r,
                 const float* __restrict__ W2l, const float* __restrict__ W2r,
                 ushort* __restrict__ Wc1, ushort* __restrict__ Wc2) {
    const int b = blockIdx.x;
    const int tid = threadIdx.x;
    if (b < eb) {
        int e = b * 256 + tid;
        if (e < E) atomicAdd(&deg[dst[e]], 1);
    } else {
        int idx = (b - eb) * 256 + tid;
        const int n1 = (512 * 512) / 8;
        const int n2 = (256 * 256) / 8;
        const float* src;
        ushort* dstp;
        if (idx < n1) {
            int e = idx * 8;
            int row = e >> 9, col = e & 511;
            src = (row < 256) ? &W1l[row * 512 + col] : &W1r[(row - 256) * 512 + col];
            dstp = &Wc1[e];
        } else if (idx < n1 + n2) {
            int e = (idx - n1) * 8;
            int row = e >> 8, col = e & 255;
            src = (row < 128) ? &W2l[row * 256 + col] : &W2r[(row - 128) * 256 + col];
            dstp = &Wc2[e];
        } else {
            return;
        }
        const float4* s4 = reinterpret_cast<const float4*>(src);
        float4 v0 = s4[0], v1 = s4[1];
        short8 o;
        o[0] = (short)f2b(v0.x); o[1] = (short)f2b(v0.y);
        o[2] = (short)f2b(v0.z); o[3] = (short)f2b(v0.w);
        o[4] = (short)f2b(v1.x); o[5] = (short)f2b(v1.y);
        o[6] = (short)f2b(v1.z); o[7] = (short)f2b(v1.w);
        *reinterpret_cast<short8*>(dstp) = o;
    }
}

// ---------------- scan (3-phase) ----------------

__global__ __launch_bounds__(256)
void scan_phase1(const int* __restrict__ deg, int* __restrict__ bsum, int n) {
    __shared__ int red[256];
    const int t = threadIdx.x;
    const int i = blockIdx.x * 1024 + t * 4;
    int s = 0;
    if (i + 4 <= n) {
        int4 v = *reinterpret_cast<const int4*>(&deg[i]);
        s = v.x + v.y + v.z + v.w;
    } else {
        for (int k = i; k < n; ++k) s += deg[k];
    }
    red[t] = s;
    __syncthreads();
#pragma unroll
    for (int off = 128; off > 0; off >>= 1) {
        if (t < off) red[t] += red[t + off];
        __syncthreads();
    }
    if (t == 0) bsum[blockIdx.x] = red[0];
}

__global__ __launch_bounds__(256)
void scan_phase2(int* __restrict__ bsum, int* __restrict__ rowptr, int nb, int n) {
    __shared__ int sh[256];
    const int t = threadIdx.x;
    int orig = (t < nb) ? bsum[t] : 0;
    sh[t] = orig;
    __syncthreads();
#pragma unroll
    for (int off = 1; off < 256; off <<= 1) {
        int v = (t >= off) ? sh[t - off] : 0;
        __syncthreads();
        sh[t] += v;
        __syncthreads();
    }
    if (t < nb) bsum[t] = sh[t] - orig;          // exclusive block offsets
    if (t == 255) rowptr[n] = sh[255];           // total
}

// phase 3 also zero-fills cursor (replaces a memset launch)
__global__ __launch_bounds__(256)
void scan_phase3(const int* __restrict__ deg, const int* __restrict__ bsum,
                 int* __restrict__ rowptr, int* __restrict__ cursor, int n) {
    __shared__ int red[256];
    const int t = threadIdx.x;
    const int i = blockIdx.x * 1024 + t * 4;
    int v0 = 0, v1 = 0, v2 = 0, v3 = 0;
    if (i + 4 <= n) {
        int4 v = *reinterpret_cast<const int4*>(&deg[i]);
        v0 = v.x; v1 = v.y; v2 = v.z; v3 = v.w;
    } else {
        if (i     < n) v0 = deg[i];
        if (i + 1 < n) v1 = deg[i + 1];
        if (i + 2 < n) v2 = deg[i + 2];
        if (i + 3 < n) v3 = deg[i + 3];
    }
    int s = v0 + v1 + v2 + v3;
    red[t] = s;
    __syncthreads();
#pragma unroll
    for (int off = 1; off < 256; off <<= 1) {
        int u = (t >= off) ? red[t - off] : 0;
        __syncthreads();
        red[t] += u;
        __syncthreads();
    }
    int pre = bsum[blockIdx.x] + red[t] - s;
    if (i + 4 <= n) {
        int4 o;
        o.x = pre; o.y = pre + v0; o.z = pre + v0 + v1; o.w = pre + v0 + v1 + v2;
        *reinterpret_cast<int4*>(&rowptr[i]) = o;
        *reinterpret_cast<int4*>(&cursor[i]) = make_int4(0, 0, 0, 0);
    } else {
        if (i     < n) { rowptr[i]     = pre;              cursor[i]     = 0; }
        if (i + 1 < n) { rowptr[i + 1] = pre + v0;         cursor[i + 1] = 0; }
        if (i + 2 < n) { rowptr[i + 2] = pre + v0 + v1;    cursor[i + 2] = 0; }
        if (i + 3 < n) { rowptr[i + 3] = pre + v0 + v1 + v2; cursor[i + 3] = 0; }
    }
}

__global__ void scatter_kernel(const int* __restrict__ src, const int* __restrict__ dst,
                               const int* __restrict__ rowptr, int* __restrict__ cursor,
                               int* __restrict__ adj, int E) {
    int e = blockIdx.x * blockDim.x + threadIdx.x;
    if (e < E) {
        int d = dst[e];
        int p = atomicAdd(&cursor[d], 1);
        adj[rowptr[d] + p] = src[e];
    }
}

// ---------------- bf16 MFMA GEMM (R7-proven): [Cl|Cr] = A @ B^T ----------------
// 128x256 tile, BK=64, 512 threads = 8 waves (each 64x64), 16x16x32 MFMA.
// B staged via global_load_lds (pre-swizzled src, linear dest).
// A: CASTA ? pipelined fp32 reg-load -> bf16 pack -> swizzled ds_write
//          : global_load_lds like B.
// LDS granule (r, g) lives at byte r*128 + ((g*16) ^ ((r&7)<<4)).

template <bool CASTA>
__global__ __launch_bounds__(512, 4)
void gemm_wide(const float* __restrict__ Af, const ushort* __restrict__ Ab,
               const ushort* __restrict__ B,
               ushort* __restrict__ Cl, ushort* __restrict__ Cr,
               int M, int K, int Ncols, int S) {
    __shared__ ushort As[128 * 64];   // 16 KB
    __shared__ ushort Bs[256 * 64];   // 32 KB
    const int tid  = threadIdx.x;
    const int wave = tid >> 6;
    const int lane = tid & 63;
    const int row0 = blockIdx.y * 128;
    const int col0 = blockIdx.x * 256;
    const int wm = (wave & 1) * 64;
    const int wn = (wave >> 1) * 64;

    floatx4 acc[4][4];
#pragma unroll
    for (int i = 0; i < 4; ++i)
#pragma unroll
        for (int j = 0; j < 4; ++j)
            acc[i][j] = (floatx4){0.f, 0.f, 0.f, 0.f};

    const int rsub = lane >> 3;                        // row within 8-row chunk
    const int ksw  = ((lane & 7) * 16) ^ (rsub << 4);  // pre-swizzled byte-in-row

    // CASTA addressing: thread owns row r = tid>>2, quarter qt = tid&3
    const int ar = tid >> 2;
    const int aq = tid & 3;
    int agrow = row0 + ar; if (agrow >= M) agrow = M - 1;
    const float* arow_base = CASTA ? (Af + (size_t)agrow * K + aq * 16) : nullptr;
    char* alds = (char*)As + ar * 128;
    const int arx = (ar & 7) << 4;

    float4 va0, va1, va2, va3;
    if constexpr (CASTA) {
        const float* s0 = arow_base;                   // k0 = 0 prologue
        va0 = *reinterpret_cast<const float4*>(s0 + 0);
        va1 = *reinterpret_cast<const float4*>(s0 + 4);
        va2 = *reinterpret_cast<const float4*>(s0 + 8);
        va3 = *reinterpret_cast<const float4*>(s0 + 12);
    }

    for (int k0 = 0; k0 < K; k0 += 64) {
        // ---- issue B DMA first (longest queue) : 32 chunks, 4 per wave ----
#pragma unroll
        for (int i = 0; i < 4; ++i) {
            int chunk = wave * 4 + i;
            int r = chunk * 8 + rsub;
            int gcol = col0 + r;                       // Ncols % 256 == 0
            const char* src = (const char*)(B + (size_t)gcol * K + k0) + ksw;
            __builtin_amdgcn_global_load_lds(
                (const __attribute__((address_space(1))) unsigned int*)src,
                (__attribute__((address_space(3))) unsigned int*)(&Bs[chunk * 512]),
                16, 0, 0);
        }
        // ---- stage A ----
        if constexpr (CASTA) {
            // pack current regs -> LDS (2 granules of 8 bf16)
            uint4 o0 = make_uint4(pk2(va0.x, va0.y), pk2(va0.z, va0.w),
                                  pk2(va1.x, va1.y), pk2(va1.z, va1.w));
            uint4 o1 = make_uint4(pk2(va2.x, va2.y), pk2(va2.z, va2.w),
                                  pk2(va3.x, va3.y), pk2(va3.z, va3.w));
            int g0 = aq * 2;
            *reinterpret_cast<uint4*>(alds + ((g0 * 16) ^ arx))       = o0;
            *reinterpret_cast<uint4*>(alds + (((g0 + 1) * 16) ^ arx)) = o1;
            // prefetch next k-tile (drained by the barrier below)
            if (k0 + 64 < K) {
                const float* s1 = arow_base + k0 + 64;
                va0 = *reinterpret_cast<const float4*>(s1 + 0);
                va1 = *reinterpret_cast<const float4*>(s1 + 4);
                va2 = *reinterpret_cast<const float4*>(s1 + 8);
                va3 = *reinterpret_cast<const float4*>(s1 + 12);
            }
        } else {
            // 16 chunks, 2 per wave
#pragma unroll
            for (int i = 0; i < 2; ++i) {
                int chunk = wave * 2 + i;
                int r = chunk * 8 + rsub;
                int grow = row0 + r;
                if (grow >= M) grow = M - 1;           // clamp (stores guarded)
                const char* src = (const char*)(Ab + (size_t)grow * K + k0) + ksw;
                __builtin_amdgcn_global_load_lds(
                    (const __attribute__((address_space(1))) unsigned int*)src,
                    (__attribute__((address_space(3))) unsigned int*)(&As[chunk * 512]),
                    16, 0, 0);
            }
        }
        __syncthreads();

#pragma unroll
        for (int kk = 0; kk < 2; ++kk) {
            short8 af[4], bf[4];
            const int kb = (kk * 64 + ((lane >> 4) << 4)) ^ ((lane & 7) << 4);
#pragma unroll
            for (int im = 0; im < 4; ++im) {
                int r = wm + im * 16 + (lane & 15);
                af[im] = *reinterpret_cast<const short8*>((const char*)As + r * 128 + kb);
            }
#pragma unroll
            for (int in = 0; in < 4; ++in) {
                int r = wn + in * 16 + (lane & 15);
                bf[in] = *reinterpret_cast<const short8*>((const char*)Bs + r * 128 + kb);
            }
#pragma unroll
            for (int im = 0; im < 4; ++im)
#pragma unroll
                for (int in = 0; in < 4; ++in)
                    acc[im][in] = __builtin_amdgcn_mfma_f32_16x16x32_bf16(
                        af[im], bf[in], acc[im][in], 0, 0, 0);
        }
        __syncthreads();
    }

    // epilogue: C/D layout col=lane&15, row=(lane>>4)*4+reg
#pragma unroll
    for (int im = 0; im < 4; ++im) {
#pragma unroll
        for (int reg = 0; reg < 4; ++reg) {
            int r = row0 + wm + im * 16 + ((lane >> 4) << 2) + reg;
            if (r < M) {
#pragma unroll
                for (int in = 0; in < 4; ++in) {
                    int g = col0 + wn + in * 16 + (lane & 15);
                    if (g < S) Cl[(size_t)r * S + g] = f2b(acc[im][in][reg]);
                    else       Cr[(size_t)r * S + (g - S)] = f2b(acc[im][in][reg]);
                }
            }
        }
    }
}

// ---------------- agg1: h = relu(mean_l + self_r + b), bf16 (R7-proven) ------
// Yl/Yr = [N, F] split buffers. LPN lanes/node, 8 ch/lane (16B short8 loads).
// Edge loop unrolled x4: 4 x 16B in flight per lane.

template <int LPN>
__global__ __launch_bounds__(256)
void aggregate_bf16(const ushort* __restrict__ Yl, const ushort* __restrict__ Yr,
                    const float* __restrict__ bias,
                    const int* __restrict__ rowptr, const int* __restrict__ adj,
                    ushort* __restrict__ H, int n) {
    constexpr int F = LPN * 8;
    const int grp = threadIdx.x / LPN;
    const int sub = threadIdx.x % LPN;
    const int node = blockIdx.x * (256 / LPN) + grp;
    if (node >= n) return;
    const int c = sub * 8;
    const int start = rowptr[node], end = rowptr[node + 1];

    float acc[8];
#pragma unroll
    for (int v = 0; v < 8; ++v) acc[v] = 0.f;

    int e = start;
    for (; e + 4 <= end; e += 4) {
        int s0 = adj[e + 0], s1 = adj[e + 1], s2 = adj[e + 2], s3 = adj[e + 3];
        short8 r0 = *reinterpret_cast<const short8*>(&Yl[(size_t)s0 * F + c]);
        short8 r1 = *reinterpret_cast<const short8*>(&Yl[(size_t)s1 * F + c]);
        short8 r2 = *reinterpret_cast<const short8*>(&Yl[(size_t)s2 * F + c]);
        short8 r3 = *reinterpret_cast<const short8*>(&Yl[(size_t)s3 * F + c]);
#pragma unroll
        for (int v = 0; v < 8; ++v)
            acc[v] += (b2f((ushort)r0[v]) + b2f((ushort)r1[v])) +
                      (b2f((ushort)r2[v]) + b2f((ushort)r3[v]));
    }
    for (; e < end; ++e) {
        int s = adj[e];
        short8 r = *reinterpret_cast<const short8*>(&Yl[(size_t)s * F + c]);
#pragma unroll
        for (int v = 0; v < 8; ++v) acc[v] += b2f((ushort)r[v]);
    }

    const int d = end - start;
    const float inv = 1.0f / (float)(d > 0 ? d : 1);
    short8 sv = *reinterpret_cast<const short8*>(&Yr[(size_t)node * F + c]);
    float4 bv0 = *reinterpret_cast<const float4*>(&bias[c]);
    float4 bv1 = *reinterpret_cast<const float4*>(&bias[c + 4]);
    float bb[8] = {bv0.x, bv0.y, bv0.z, bv0.w, bv1.x, bv1.y, bv1.z, bv1.w};
    short8 o;
#pragma unroll
    for (int v = 0; v < 8; ++v)
        o[v] = (short)f2b(fmaxf(acc[v] * inv + b2f((ushort)sv[v]) + bb[v], 0.f));
    *reinterpret_cast<short8*>(&H[(size_t)node * F + c]) = o;
}

// ---------------- agg2 + params fused: P = relu(agg(z)) @ Wp^T + bp ----------
// F=128, 16 lanes/node (8 ch/lane). After computing h2 in fp32 registers,
// lane accumulates 28 partial dot-products over its 8 channels, then a 4-step
// __shfl_xor reduce across the 16-lane group yields full p[28] in every lane;
// lanes 0..13 write 2 floats each. h2 is never materialized.

__global__ __launch_bounds__(256)
void agg2_params(const ushort* __restrict__ Zl, const ushort* __restrict__ Zr,
                 const float* __restrict__ bias,
                 const int* __restrict__ rowptr, const int* __restrict__ adj,
                 const float* __restrict__ Wp, const float* __restrict__ bp,
                 float* __restrict__ P, int n) {
    constexpr int F = 128;
    __shared__ float WpS[28 * 128];   // 14 KB, row-major [j][c]
    __shared__ float bpS[28];
    for (int t = threadIdx.x; t < 28 * 128; t += 256) WpS[t] = Wp[t];
    if (threadIdx.x < 28) bpS[threadIdx.x] = bp[threadIdx.x];
    __syncthreads();

    const int grp = threadIdx.x >> 4;          // node group 0..15
    const int sub = threadIdx.x & 15;
    const int node = blockIdx.x * 16 + grp;
    if (node >= n) return;
    const int c = sub * 8;
    const int start = rowptr[node], end = rowptr[node + 1];

    float acc[8];
#pragma unroll
    for (int v = 0; v < 8; ++v) acc[v] = 0.f;

    int e = start;
    for (; e + 4 <= end; e += 4) {
        int s0 = adj[e + 0], s1 = adj[e + 1], s2 = adj[e + 2], s3 = adj[e + 3];
        short8 r0 = *reinterpret_cast<const short8*>(&Zl[(size_t)s0 * F + c]);
        short8 r1 = *reinterpret_cast<const short8*>(&Zl[(size_t)s1 * F + c]);
        short8 r2 = *reinterpret_cast<const short8*>(&Zl[(size_t)s2 * F + c]);
        short8 r3 = *reinterpret_cast<const short8*>(&Zl[(size_t)s3 * F + c]);
#pragma unroll
        for (int v = 0; v < 8; ++v)
            acc[v] += (b2f((ushort)r0[v]) + b2f((ushort)r1[v])) +
                      (b2f((ushort)r2[v]) + b2f((ushort)r3[v]));
    }
    for (; e < end; ++e) {
        int s = adj[e];
        short8 r = *reinterpret_cast<const short8*>(&Zl[(size_t)s * F + c]);
#pragma unroll
        for (int v = 0; v < 8; ++v) acc[v] += b2f((ushort)r[v]);
    }

    const int d = end - start;
    const float inv = 1.0f / (float)(d > 0 ? d : 1);
    short8 sv = *reinterpret_cast<const short8*>(&Zr[(size_t)node * F + c]);
    float4 bv0 = *reinterpret_cast<const float4*>(&bias[c]);
    float4 bv1 = *reinterpret_cast<const float4*>(&bias[c + 4]);
    float bb[8] = {bv0.x, bv0.y, bv0.z, bv0.w, bv1.x, bv1.y, bv1.z, bv1.w};
    float hv[8];
#pragma unroll
    for (int v = 0; v < 8; ++v)
        hv[v] = fmaxf(acc[v] * inv + b2f((ushort)sv[v]) + bb[v], 0.f);

    // 28 partial dot-products over this lane's 8 channels
    float p[28];
#pragma unroll
    for (int j = 0; j < 28; ++j) {
        const float* w = &WpS[j * 128 + c];
        float4 w0 = *reinterpret_cast<const float4*>(w);
        float4 w1 = *reinterpret_cast<const float4*>(w + 4);
        p[j] = hv[0] * w0.x + hv[1] * w0.y + hv[2] * w0.z + hv[3] * w0.w +
               hv[4] * w1.x + hv[5] * w1.y + hv[6] * w1.z + hv[7] * w1.w;
    }
    // reduce across the 16-lane group (xor masks < 16 stay in-group)
#pragma unroll
    for (int m = 8; m >= 1; m >>= 1) {
#pragma unroll
        for (int j = 0; j < 28; ++j)
            p[j] += __shfl_xor(p[j], m);
    }
    // every lane now holds the full sums; lanes 0..13 write 2 floats each
    if (sub < 14) {
        float2 o = make_float2(p[2 * sub] + bpS[2 * sub],
                               p[2 * sub + 1] + bpS[2 * sub + 1]);
        *reinterpret_cast<float2*>(&P[(size_t)node * 32 + 2 * sub]) = o;
    }
}

// ---------------- Cayley: O = (I-A)^{-1}(I+A) ----------------

__global__ __launch_bounds__(256)
void cayley_kernel(const float* __restrict__ P, float* __restrict__ Out, int n) {
    int i = blockIdx.x * blockDim.x + threadIdx.x;
    if (i >= n) return;
    float p[28];
    const float4* pp = reinterpret_cast<const float4*>(&P[(size_t)i * 32]);
#pragma unroll
    for (int q = 0; q < 7; ++q) {
        float4 v = pp[q];
        p[4 * q + 0] = v.x; p[4 * q + 1] = v.y;
        p[4 * q + 2] = v.z; p[4 * q + 3] = v.w;
    }

    float M_[8][8], B_[8][8];
#pragma unroll
    for (int r = 0; r < 8; ++r)
#pragma unroll
        for (int c = 0; c < 8; ++c) {
            M_[r][c] = (r == c) ? 1.f : 0.f;
            B_[r][c] = (r == c) ? 1.f : 0.f;
        }
    {
        int idx = 0;
#pragma unroll
        for (int r = 0; r < 8; ++r)
#pragma unroll
            for (int c = r + 1; c < 8; ++c) {
                float a = p[idx++];
                M_[r][c] -= a;  M_[c][r] += a;
                B_[r][c] += a;  B_[c][r] -= a;
            }
    }
#pragma unroll
    for (int col = 0; col < 8; ++col) {
        float inv = 1.0f / M_[col][col];
#pragma unroll
        for (int c = 0; c < 8; ++c) { M_[col][c] *= inv; B_[col][c] *= inv; }
#pragma unroll
        for (int r = 0; r < 8; ++r) {
            if (r == col) continue;
            float f = M_[r][col];
#pragma unroll
            for (int c = 0; c < 8; ++c) {
                M_[r][c] -= f * M_[col][c];
                B_[r][c] -= f * B_[col][c];
            }
        }
    }
    float* out = &Out[(size_t)i * 64];
#pragma unroll
    for (int r = 0; r < 8; ++r) {
        float4 o0 = make_float4(B_[r][0], B_[r][1], B_[r][2], B_[r][3]);
        float4 o1 = make_float4(B_[r][4], B_[r][5], B_[r][6], B_[r][7]);
        *reinterpret_cast<float4*>(&out[r * 8 + 0]) = o0;
        *reinterpret_cast<float4*>(&out[r * 8 + 4]) = o1;
    }
}

// ---------------------------------------------------------------------------

extern "C" void kernel_launch(void* const* d_in, const int* in_sizes, int n_in,
                              void* d_out, int out_size, void* d_ws, size_t ws_size,
                              hipStream_t stream) {
    const float* x   = (const float*)d_in[0];
    const int*   ei  = (const int*)d_in[1];
    const float* W1l = (const float*)d_in[2];
    const float* b1  = (const float*)d_in[3];
    const float* W1r = (const float*)d_in[4];
    const float* W2l = (const float*)d_in[5];
    const float* b2  = (const float*)d_in[6];
    const float* W2r = (const float*)d_in[7];
    const float* Wp  = (const float*)d_in[8];
    const float* bp  = (const float*)d_in[9];
    float* out = (float*)d_out;

    const int IN_DIM = 512;
    const int N = in_sizes[0] / IN_DIM;   // 50000
    const int E = in_sizes[1] / 2;        // 800000

    char* ws = (char*)d_ws;
    size_t off = 0;
    int* deg      = (int*)(ws + off); off = WS_ALIGN(off + (size_t)N * 4);
    int* rowptr   = (int*)(ws + off); off = WS_ALIGN(off + (size_t)(N + 1) * 4);
    int* cursor   = (int*)(ws + off); off = WS_ALIGN(off + (size_t)N * 4);
    int* bsum     = (int*)(ws + off); off = WS_ALIGN(off + (size_t)256 * 4);
    int* adj      = (int*)(ws + off); off = WS_ALIGN(off + (size_t)E * 4);
    ushort* Yl    = (ushort*)(ws + off); off = WS_ALIGN(off + (size_t)N * 256 * 2);
    ushort* Yr    = (ushort*)(ws + off); off = WS_ALIGN(off + (size_t)N * 256 * 2);
    ushort* h1    = (ushort*)(ws + off); off = WS_ALIGN(off + (size_t)N * 256 * 2);
    ushort* zl    = (ushort*)(ws + off); off = WS_ALIGN(off + (size_t)N * 128 * 2);
    ushort* zr    = (ushort*)(ws + off); off = WS_ALIGN(off + (size_t)N * 128 * 2);
    ushort* Wc1   = (ushort*)(ws + off); off = WS_ALIGN(off + (size_t)512 * 512 * 2);
    ushort* Wc2   = (ushort*)(ws + off); off = WS_ALIGN(off + (size_t)256 * 256 * 2);
    float*  Pp    = (float*)(ws + off);  off = WS_ALIGN(off + (size_t)N * 32 * 4);

    const int* src = ei;
    const int* dst = ei + E;

    hipMemsetAsync(deg, 0, (size_t)N * 4, stream);

    const int eb = (E + 255) / 256;       // 3125
    const int wb = ((512 * 512 + 256 * 256) / 8 + 255) / 256;   // 160
    const int nb = (N + 1023) / 1024;     // <= 256

    prep_kernel<<<eb + wb, 256, 0, stream>>>(
        dst, deg, E, eb, W1l, W1r, W2l, W2r, Wc1, Wc2);
    scan_phase1<<<nb, 256, 0, stream>>>(deg, bsum, N);
    scan_phase2<<<1, 256, 0, stream>>>(bsum, rowptr, nb, N);
    scan_phase3<<<nb, 256, 0, stream>>>(deg, bsum, rowptr, cursor, N);
    scatter_kernel<<<eb, 256, 0, stream>>>(src, dst, rowptr, cursor, adj, E);

    int gm = (N + 127) / 128;   // 391

    // layer 1: [Yl|Yr] = bf16(x) @ Wc1^T  (fused pipelined cast, [N,256] each)
    gemm_wide<true><<<dim3(2, gm), 512, 0, stream>>>(
        x, (const ushort*)nullptr, Wc1, Yl, Yr, N, 512, 512, 256);
    // h1 = relu(mean + self + b1)  [N,256] bf16 (32 lanes/node, 16B loads)
    aggregate_bf16<32><<<(N + 7) / 8, 256, 0, stream>>>(Yl, Yr, b1, rowptr, adj, h1, N);

    // layer 2: [zl|zr] = h1 @ Wc2^T   ([N,128] each)
    gemm_wide<false><<<dim3(1, gm), 512, 0, stream>>>(
        (const float*)nullptr, h1, Wc2, zl, zr, N, 256, 256, 128);

    // agg2 + params fused -> P [N,32] fp32 (h2 never materialized)
    agg2_params<<<(N + 15) / 16, 256, 0, stream>>>(
        zl, zr, b2, rowptr, adj, Wp, bp, Pp, N);

    // Cayley -> out [N,8,8] fp32
    cayley_kernel<<<(N + 255) / 256, 256, 0, stream>>>(Pp, out, N);
}

// Round 13
// 276.553 us; speedup vs baseline: 1.1552x; 1.1030x over previous
//
#include <hip/hip_runtime.h>
#include <hip/hip_bf16.h>

// ---------------------------------------------------------------------------
// InductiveBundleMapLearner: 2x SAGEConv (mean) -> linear -> Cayley map
// R7-proven core: fused-cast 512-thread gemm_wide (128x256), 16B 4-deep
// gather aggregation, pitch-132 params kernel, per-thread Cayley.
// Plus: fused prep (hist||wcat) and cursor-zeroing folded into scan.
// ---------------------------------------------------------------------------

#define WS_ALIGN(x) (((x) + 255) & ~size_t(255))

typedef __attribute__((ext_vector_type(8))) short short8;
typedef __attribute__((ext_vector_type(4))) float floatx4;

static __device__ __forceinline__ ushort f2b(float f) {
    unsigned u = __builtin_bit_cast(unsigned, f);
    u = (u + 0x7fffu + ((u >> 16) & 1u)) >> 16;   // RNE, finite inputs
    return (ushort)u;
}
static __device__ __forceinline__ float b2f(ushort h) {
    unsigned u = ((unsigned)h) << 16;
    return __builtin_bit_cast(float, u);
}
static __device__ __forceinline__ unsigned pk2(float a, float b) {
    return (unsigned)f2b(a) | ((unsigned)f2b(b) << 16);
}

// ---------------- fused prep: hist || build_wcat ----------------

__global__ __launch_bounds__(256)
void prep_kernel(const int* __restrict__ dst, int* __restrict__ deg, int E, int eb,
                 const float* __restrict__ W1l, const float* __restrict__ W1r,
                 const float* __restrict__ W2l, const float* __restrict__ W2r,
                 ushort* __restrict__ Wc1, ushort* __restrict__ Wc2) {
    const int b = blockIdx.x;
    const int tid = threadIdx.x;
    if (b < eb) {
        int e = b * 256 + tid;
        if (e < E) atomicAdd(&deg[dst[e]], 1);
    } else {
        int idx = (b - eb) * 256 + tid;
        const int n1 = (512 * 512) / 8;
        const int n2 = (256 * 256) / 8;
        const float* src;
        ushort* dstp;
        if (idx < n1) {
            int e = idx * 8;
            int row = e >> 9, col = e & 511;
            src = (row < 256) ? &W1l[row * 512 + col] : &W1r[(row - 256) * 512 + col];
            dstp = &Wc1[e];
        } else if (idx < n1 + n2) {
            int e = (idx - n1) * 8;
            int row = e >> 8, col = e & 255;
            src = (row < 128) ? &W2l[row * 256 + col] : &W2r[(row - 128) * 256 + col];
            dstp = &Wc2[e];
        } else {
            return;
        }
        const float4* s4 = reinterpret_cast<const float4*>(src);
        float4 v0 = s4[0], v1 = s4[1];
        short8 o;
        o[0] = (short)f2b(v0.x); o[1] = (short)f2b(v0.y);
        o[2] = (short)f2b(v0.z); o[3] = (short)f2b(v0.w);
        o[4] = (short)f2b(v1.x); o[5] = (short)f2b(v1.y);
        o[6] = (short)f2b(v1.z); o[7] = (short)f2b(v1.w);
        *reinterpret_cast<short8*>(dstp) = o;
    }
}

// ---------------- scan (3-phase) ----------------

__global__ __launch_bounds__(256)
void scan_phase1(const int* __restrict__ deg, int* __restrict__ bsum, int n) {
    __shared__ int red[256];
    const int t = threadIdx.x;
    const int i = blockIdx.x * 1024 + t * 4;
    int s = 0;
    if (i + 4 <= n) {
        int4 v = *reinterpret_cast<const int4*>(&deg[i]);
        s = v.x + v.y + v.z + v.w;
    } else {
        for (int k = i; k < n; ++k) s += deg[k];
    }
    red[t] = s;
    __syncthreads();
#pragma unroll
    for (int off = 128; off > 0; off >>= 1) {
        if (t < off) red[t] += red[t + off];
        __syncthreads();
    }
    if (t == 0) bsum[blockIdx.x] = red[0];
}

__global__ __launch_bounds__(256)
void scan_phase2(int* __restrict__ bsum, int* __restrict__ rowptr, int nb, int n) {
    __shared__ int sh[256];
    const int t = threadIdx.x;
    int orig = (t < nb) ? bsum[t] : 0;
    sh[t] = orig;
    __syncthreads();
#pragma unroll
    for (int off = 1; off < 256; off <<= 1) {
        int v = (t >= off) ? sh[t - off] : 0;
        __syncthreads();
        sh[t] += v;
        __syncthreads();
    }
    if (t < nb) bsum[t] = sh[t] - orig;          // exclusive block offsets
    if (t == 255) rowptr[n] = sh[255];           // total
}

// phase 3 also zero-fills cursor (replaces a memset launch)
__global__ __launch_bounds__(256)
void scan_phase3(const int* __restrict__ deg, const int* __restrict__ bsum,
                 int* __restrict__ rowptr, int* __restrict__ cursor, int n) {
    __shared__ int red[256];
    const int t = threadIdx.x;
    const int i = blockIdx.x * 1024 + t * 4;
    int v0 = 0, v1 = 0, v2 = 0, v3 = 0;
    if (i + 4 <= n) {
        int4 v = *reinterpret_cast<const int4*>(&deg[i]);
        v0 = v.x; v1 = v.y; v2 = v.z; v3 = v.w;
    } else {
        if (i     < n) v0 = deg[i];
        if (i + 1 < n) v1 = deg[i + 1];
        if (i + 2 < n) v2 = deg[i + 2];
        if (i + 3 < n) v3 = deg[i + 3];
    }
    int s = v0 + v1 + v2 + v3;
    red[t] = s;
    __syncthreads();
#pragma unroll
    for (int off = 1; off < 256; off <<= 1) {
        int u = (t >= off) ? red[t - off] : 0;
        __syncthreads();
        red[t] += u;
        __syncthreads();
    }
    int pre = bsum[blockIdx.x] + red[t] - s;
    if (i + 4 <= n) {
        int4 o;
        o.x = pre; o.y = pre + v0; o.z = pre + v0 + v1; o.w = pre + v0 + v1 + v2;
        *reinterpret_cast<int4*>(&rowptr[i]) = o;
        *reinterpret_cast<int4*>(&cursor[i]) = make_int4(0, 0, 0, 0);
    } else {
        if (i     < n) { rowptr[i]     = pre;                cursor[i]     = 0; }
        if (i + 1 < n) { rowptr[i + 1] = pre + v0;           cursor[i + 1] = 0; }
        if (i + 2 < n) { rowptr[i + 2] = pre + v0 + v1;      cursor[i + 2] = 0; }
        if (i + 3 < n) { rowptr[i + 3] = pre + v0 + v1 + v2; cursor[i + 3] = 0; }
    }
}

__global__ void scatter_kernel(const int* __restrict__ src, const int* __restrict__ dst,
                               const int* __restrict__ rowptr, int* __restrict__ cursor,
                               int* __restrict__ adj, int E) {
    int e = blockIdx.x * blockDim.x + threadIdx.x;
    if (e < E) {
        int d = dst[e];
        int p = atomicAdd(&cursor[d], 1);
        adj[rowptr[d] + p] = src[e];
    }
}

// ---------------- bf16 MFMA GEMM (R7-proven): [Cl|Cr] = A @ B^T ----------------
// 128x256 tile, BK=64, 512 threads = 8 waves (each 64x64), 16x16x32 MFMA.
// B staged via global_load_lds (pre-swizzled src, linear dest).
// A: CASTA ? pipelined fp32 reg-load -> bf16 pack -> swizzled ds_write
//          : global_load_lds like B.
// LDS granule (r, g) lives at byte r*128 + ((g*16) ^ ((r&7)<<4)).

template <bool CASTA>
__global__ __launch_bounds__(512, 4)
void gemm_wide(const float* __restrict__ Af, const ushort* __restrict__ Ab,
               const ushort* __restrict__ B,
               ushort* __restrict__ Cl, ushort* __restrict__ Cr,
               int M, int K, int Ncols, int S) {
    __shared__ ushort As[128 * 64];   // 16 KB
    __shared__ ushort Bs[256 * 64];   // 32 KB
    const int tid  = threadIdx.x;
    const int wave = tid >> 6;
    const int lane = tid & 63;
    const int row0 = blockIdx.y * 128;
    const int col0 = blockIdx.x * 256;
    const int wm = (wave & 1) * 64;
    const int wn = (wave >> 1) * 64;

    floatx4 acc[4][4];
#pragma unroll
    for (int i = 0; i < 4; ++i)
#pragma unroll
        for (int j = 0; j < 4; ++j)
            acc[i][j] = (floatx4){0.f, 0.f, 0.f, 0.f};

    const int rsub = lane >> 3;                        // row within 8-row chunk
    const int ksw  = ((lane & 7) * 16) ^ (rsub << 4);  // pre-swizzled byte-in-row

    // CASTA addressing: thread owns row r = tid>>2, quarter qt = tid&3
    const int ar = tid >> 2;
    const int aq = tid & 3;
    int agrow = row0 + ar; if (agrow >= M) agrow = M - 1;
    const float* arow_base = CASTA ? (Af + (size_t)agrow * K + aq * 16) : nullptr;
    char* alds = (char*)As + ar * 128;
    const int arx = (ar & 7) << 4;

    float4 va0, va1, va2, va3;
    if constexpr (CASTA) {
        const float* s0 = arow_base;                   // k0 = 0 prologue
        va0 = *reinterpret_cast<const float4*>(s0 + 0);
        va1 = *reinterpret_cast<const float4*>(s0 + 4);
        va2 = *reinterpret_cast<const float4*>(s0 + 8);
        va3 = *reinterpret_cast<const float4*>(s0 + 12);
    }

    for (int k0 = 0; k0 < K; k0 += 64) {
        // ---- issue B DMA first (longest queue) : 32 chunks, 4 per wave ----
#pragma unroll
        for (int i = 0; i < 4; ++i) {
            int chunk = wave * 4 + i;
            int r = chunk * 8 + rsub;
            int gcol = col0 + r;                       // Ncols % 256 == 0
            const char* src = (const char*)(B + (size_t)gcol * K + k0) + ksw;
            __builtin_amdgcn_global_load_lds(
                (const __attribute__((address_space(1))) unsigned int*)src,
                (__attribute__((address_space(3))) unsigned int*)(&Bs[chunk * 512]),
                16, 0, 0);
        }
        // ---- stage A ----
        if constexpr (CASTA) {
            // pack current regs -> LDS (2 granules of 8 bf16)
            uint4 o0 = make_uint4(pk2(va0.x, va0.y), pk2(va0.z, va0.w),
                                  pk2(va1.x, va1.y), pk2(va1.z, va1.w));
            uint4 o1 = make_uint4(pk2(va2.x, va2.y), pk2(va2.z, va2.w),
                                  pk2(va3.x, va3.y), pk2(va3.z, va3.w));
            int g0 = aq * 2;
            *reinterpret_cast<uint4*>(alds + ((g0 * 16) ^ arx))       = o0;
            *reinterpret_cast<uint4*>(alds + (((g0 + 1) * 16) ^ arx)) = o1;
            // prefetch next k-tile (drained by the barrier below)
            if (k0 + 64 < K) {
                const float* s1 = arow_base + k0 + 64;
                va0 = *reinterpret_cast<const float4*>(s1 + 0);
                va1 = *reinterpret_cast<const float4*>(s1 + 4);
                va2 = *reinterpret_cast<const float4*>(s1 + 8);
                va3 = *reinterpret_cast<const float4*>(s1 + 12);
            }
        } else {
            // 16 chunks, 2 per wave
#pragma unroll
            for (int i = 0; i < 2; ++i) {
                int chunk = wave * 2 + i;
                int r = chunk * 8 + rsub;
                int grow = row0 + r;
                if (grow >= M) grow = M - 1;           // clamp (stores guarded)
                const char* src = (const char*)(Ab + (size_t)grow * K + k0) + ksw;
                __builtin_amdgcn_global_load_lds(
                    (const __attribute__((address_space(1))) unsigned int*)src,
                    (__attribute__((address_space(3))) unsigned int*)(&As[chunk * 512]),
                    16, 0, 0);
            }
        }
        __syncthreads();

#pragma unroll
        for (int kk = 0; kk < 2; ++kk) {
            short8 af[4], bf[4];
            const int kb = (kk * 64 + ((lane >> 4) << 4)) ^ ((lane & 7) << 4);
#pragma unroll
            for (int im = 0; im < 4; ++im) {
                int r = wm + im * 16 + (lane & 15);
                af[im] = *reinterpret_cast<const short8*>((const char*)As + r * 128 + kb);
            }
#pragma unroll
            for (int in = 0; in < 4; ++in) {
                int r = wn + in * 16 + (lane & 15);
                bf[in] = *reinterpret_cast<const short8*>((const char*)Bs + r * 128 + kb);
            }
#pragma unroll
            for (int im = 0; im < 4; ++im)
#pragma unroll
                for (int in = 0; in < 4; ++in)
                    acc[im][in] = __builtin_amdgcn_mfma_f32_16x16x32_bf16(
                        af[im], bf[in], acc[im][in], 0, 0, 0);
        }
        __syncthreads();
    }

    // epilogue: C/D layout col=lane&15, row=(lane>>4)*4+reg
#pragma unroll
    for (int im = 0; im < 4; ++im) {
#pragma unroll
        for (int reg = 0; reg < 4; ++reg) {
            int r = row0 + wm + im * 16 + ((lane >> 4) << 2) + reg;
            if (r < M) {
#pragma unroll
                for (int in = 0; in < 4; ++in) {
                    int g = col0 + wn + in * 16 + (lane & 15);
                    if (g < S) Cl[(size_t)r * S + g] = f2b(acc[im][in][reg]);
                    else       Cr[(size_t)r * S + (g - S)] = f2b(acc[im][in][reg]);
                }
            }
        }
    }
}

// ---------------- aggregation: h = relu(mean_l + self_r + b), bf16 ----------------
// Yl/Yr = [N, F] split buffers. LPN lanes/node, 8 ch/lane (16B short8 loads).
// Edge loop unrolled x4: 4 x 16B in flight per lane.

template <int LPN>
__global__ __launch_bounds__(256)
void aggregate_bf16(const ushort* __restrict__ Yl, const ushort* __restrict__ Yr,
                    const float* __restrict__ bias,
                    const int* __restrict__ rowptr, const int* __restrict__ adj,
                    ushort* __restrict__ H, int n) {
    constexpr int F = LPN * 8;
    const int grp = threadIdx.x / LPN;
    const int sub = threadIdx.x % LPN;
    const int node = blockIdx.x * (256 / LPN) + grp;
    if (node >= n) return;
    const int c = sub * 8;
    const int start = rowptr[node], end = rowptr[node + 1];

    float acc[8];
#pragma unroll
    for (int v = 0; v < 8; ++v) acc[v] = 0.f;

    int e = start;
    for (; e + 4 <= end; e += 4) {
        int s0 = adj[e + 0], s1 = adj[e + 1], s2 = adj[e + 2], s3 = adj[e + 3];
        short8 r0 = *reinterpret_cast<const short8*>(&Yl[(size_t)s0 * F + c]);
        short8 r1 = *reinterpret_cast<const short8*>(&Yl[(size_t)s1 * F + c]);
        short8 r2 = *reinterpret_cast<const short8*>(&Yl[(size_t)s2 * F + c]);
        short8 r3 = *reinterpret_cast<const short8*>(&Yl[(size_t)s3 * F + c]);
#pragma unroll
        for (int v = 0; v < 8; ++v)
            acc[v] += (b2f((ushort)r0[v]) + b2f((ushort)r1[v])) +
                      (b2f((ushort)r2[v]) + b2f((ushort)r3[v]));
    }
    for (; e < end; ++e) {
        int s = adj[e];
        short8 r = *reinterpret_cast<const short8*>(&Yl[(size_t)s * F + c]);
#pragma unroll
        for (int v = 0; v < 8; ++v) acc[v] += b2f((ushort)r[v]);
    }

    const int d = end - start;
    const float inv = 1.0f / (float)(d > 0 ? d : 1);
    short8 sv = *reinterpret_cast<const short8*>(&Yr[(size_t)node * F + c]);
    float4 bv0 = *reinterpret_cast<const float4*>(&bias[c]);
    float4 bv1 = *reinterpret_cast<const float4*>(&bias[c + 4]);
    float bb[8] = {bv0.x, bv0.y, bv0.z, bv0.w, bv1.x, bv1.y, bv1.z, bv1.w};
    short8 o;
#pragma unroll
    for (int v = 0; v < 8; ++v)
        o[v] = (short)f2b(fmaxf(acc[v] * inv + b2f((ushort)sv[v]) + bb[v], 0.f));
    *reinterpret_cast<short8*>(&H[(size_t)node * F + c]) = o;
}

// ---------------- params: p = h2 @ Wp^T + bp -> P[N,32] ----------------
// 8 lanes/node; lane l owns params {l, l+8, l+16, l+24}; pitch-132 LDS
// (lane word-stride 132*l -> bank stride 4 -> conflict-free float4 reads).

__global__ __launch_bounds__(256)
void params_kernel(const ushort* __restrict__ H2, const float* __restrict__ Wp,
                   const float* __restrict__ bp, float* __restrict__ P, int n) {
    __shared__ float WpS[32 * 132];
    __shared__ float bpS[32];
    for (int t = threadIdx.x; t < 32 * 132; t += 256) WpS[t] = 0.f;
    if (threadIdx.x < 32) bpS[threadIdx.x] = (threadIdx.x < 28) ? bp[threadIdx.x] : 0.f;
    __syncthreads();
    for (int t = threadIdx.x; t < 28 * 128; t += 256) {
        int r = t >> 7, c = t & 127;
        WpS[r * 132 + c] = Wp[t];
    }
    __syncthreads();

    const int node = blockIdx.x * 32 + (threadIdx.x >> 3);
    const int l = threadIdx.x & 7;
    if (node >= n) return;

    short8 h8[16];
    const short8* hp = reinterpret_cast<const short8*>(&H2[(size_t)node * 128]);
#pragma unroll
    for (int q = 0; q < 16; ++q) h8[q] = hp[q];

    float acc0 = bpS[l], acc1 = bpS[l + 8], acc2 = bpS[l + 16], acc3 = bpS[l + 24];
#pragma unroll
    for (int q = 0; q < 32; ++q) {
        float h0 = b2f((ushort)h8[q >> 1][(q & 1) * 4 + 0]);
        float h1 = b2f((ushort)h8[q >> 1][(q & 1) * 4 + 1]);
        float h2 = b2f((ushort)h8[q >> 1][(q & 1) * 4 + 2]);
        float h3 = b2f((ushort)h8[q >> 1][(q & 1) * 4 + 3]);
        float4 w0 = *reinterpret_cast<const float4*>(&WpS[(l +  0) * 132 + 4 * q]);
        float4 w1 = *reinterpret_cast<const float4*>(&WpS[(l +  8) * 132 + 4 * q]);
        float4 w2 = *reinterpret_cast<const float4*>(&WpS[(l + 16) * 132 + 4 * q]);
        float4 w3 = *reinterpret_cast<const float4*>(&WpS[(l + 24) * 132 + 4 * q]);
        acc0 += h0 * w0.x + h1 * w0.y + h2 * w0.z + h3 * w0.w;
        acc1 += h0 * w1.x + h1 * w1.y + h2 * w1.z + h3 * w1.w;
        acc2 += h0 * w2.x + h1 * w2.y + h2 * w2.z + h3 * w2.w;
        acc3 += h0 * w3.x + h1 * w3.y + h2 * w3.z + h3 * w3.w;
    }
    float* pout = &P[(size_t)node * 32];
    pout[l]      = acc0;
    pout[l + 8]  = acc1;
    pout[l + 16] = acc2;
    pout[l + 24] = acc3;
}

// ---------------- Cayley: O = (I-A)^{-1}(I+A) ----------------

__global__ __launch_bounds__(256)
void cayley_kernel(const float* __restrict__ P, float* __restrict__ Out, int n) {
    int i = blockIdx.x * blockDim.x + threadIdx.x;
    if (i >= n) return;
    float p[28];
    const float4* pp = reinterpret_cast<const float4*>(&P[(size_t)i * 32]);
#pragma unroll
    for (int q = 0; q < 7; ++q) {
        float4 v = pp[q];
        p[4 * q + 0] = v.x; p[4 * q + 1] = v.y;
        p[4 * q + 2] = v.z; p[4 * q + 3] = v.w;
    }

    float M_[8][8], B_[8][8];
#pragma unroll
    for (int r = 0; r < 8; ++r)
#pragma unroll
        for (int c = 0; c < 8; ++c) {
            M_[r][c] = (r == c) ? 1.f : 0.f;
            B_[r][c] = (r == c) ? 1.f : 0.f;
        }
    {
        int idx = 0;
#pragma unroll
        for (int r = 0; r < 8; ++r)
#pragma unroll
            for (int c = r + 1; c < 8; ++c) {
                float a = p[idx++];
                M_[r][c] -= a;  M_[c][r] += a;
                B_[r][c] += a;  B_[c][r] -= a;
            }
    }
#pragma unroll
    for (int col = 0; col < 8; ++col) {
        float inv = 1.0f / M_[col][col];
#pragma unroll
        for (int c = 0; c < 8; ++c) { M_[col][c] *= inv; B_[col][c] *= inv; }
#pragma unroll
        for (int r = 0; r < 8; ++r) {
            if (r == col) continue;
            float f = M_[r][col];
#pragma unroll
            for (int c = 0; c < 8; ++c) {
                M_[r][c] -= f * M_[col][c];
                B_[r][c] -= f * B_[col][c];
            }
        }
    }
    float* out = &Out[(size_t)i * 64];
#pragma unroll
    for (int r = 0; r < 8; ++r) {
        float4 o0 = make_float4(B_[r][0], B_[r][1], B_[r][2], B_[r][3]);
        float4 o1 = make_float4(B_[r][4], B_[r][5], B_[r][6], B_[r][7]);
        *reinterpret_cast<float4*>(&out[r * 8 + 0]) = o0;
        *reinterpret_cast<float4*>(&out[r * 8 + 4]) = o1;
    }
}

// ---------------------------------------------------------------------------

extern "C" void kernel_launch(void* const* d_in, const int* in_sizes, int n_in,
                              void* d_out, int out_size, void* d_ws, size_t ws_size,
                              hipStream_t stream) {
    const float* x   = (const float*)d_in[0];
    const int*   ei  = (const int*)d_in[1];
    const float* W1l = (const float*)d_in[2];
    const float* b1  = (const float*)d_in[3];
    const float* W1r = (const float*)d_in[4];
    const float* W2l = (const float*)d_in[5];
    const float* b2  = (const float*)d_in[6];
    const float* W2r = (const float*)d_in[7];
    const float* Wp  = (const float*)d_in[8];
    const float* bp  = (const float*)d_in[9];
    float* out = (float*)d_out;

    const int IN_DIM = 512;
    const int N = in_sizes[0] / IN_DIM;   // 50000
    const int E = in_sizes[1] / 2;        // 800000

    char* ws = (char*)d_ws;
    size_t off = 0;
    int* deg      = (int*)(ws + off); off = WS_ALIGN(off + (size_t)N * 4);
    int* rowptr   = (int*)(ws + off); off = WS_ALIGN(off + (size_t)(N + 1) * 4);
    int* cursor   = (int*)(ws + off); off = WS_ALIGN(off + (size_t)N * 4);
    int* bsum     = (int*)(ws + off); off = WS_ALIGN(off + (size_t)256 * 4);
    int* adj      = (int*)(ws + off); off = WS_ALIGN(off + (size_t)E * 4);
    ushort* Yl    = (ushort*)(ws + off); off = WS_ALIGN(off + (size_t)N * 256 * 2);
    ushort* Yr    = (ushort*)(ws + off); off = WS_ALIGN(off + (size_t)N * 256 * 2);
    ushort* h1    = (ushort*)(ws + off); off = WS_ALIGN(off + (size_t)N * 256 * 2);
    ushort* zl    = (ushort*)(ws + off); off = WS_ALIGN(off + (size_t)N * 128 * 2);
    ushort* zr    = (ushort*)(ws + off); off = WS_ALIGN(off + (size_t)N * 128 * 2);
    ushort* Wc1   = (ushort*)(ws + off); off = WS_ALIGN(off + (size_t)512 * 512 * 2);
    ushort* Wc2   = (ushort*)(ws + off); off = WS_ALIGN(off + (size_t)256 * 256 * 2);
    float*  Pp    = (float*)(ws + off);  off = WS_ALIGN(off + (size_t)N * 32 * 4);

    const int* src = ei;
    const int* dst = ei + E;

    hipMemsetAsync(deg, 0, (size_t)N * 4, stream);

    const int eb = (E + 255) / 256;       // 3125
    const int wb = ((512 * 512 + 256 * 256) / 8 + 255) / 256;   // 160
    const int nb = (N + 1023) / 1024;     // <= 256

    prep_kernel<<<eb + wb, 256, 0, stream>>>(
        dst, deg, E, eb, W1l, W1r, W2l, W2r, Wc1, Wc2);
    scan_phase1<<<nb, 256, 0, stream>>>(deg, bsum, N);
    scan_phase2<<<1, 256, 0, stream>>>(bsum, rowptr, nb, N);
    scan_phase3<<<nb, 256, 0, stream>>>(deg, bsum, rowptr, cursor, N);
    scatter_kernel<<<eb, 256, 0, stream>>>(src, dst, rowptr, cursor, adj, E);

    int gm = (N + 127) / 128;   // 391

    // layer 1: [Yl|Yr] = bf16(x) @ Wc1^T  (fused pipelined cast, [N,256] each)
    gemm_wide<true><<<dim3(2, gm), 512, 0, stream>>>(
        x, (const ushort*)nullptr, Wc1, Yl, Yr, N, 512, 512, 256);
    // h1 = relu(mean + self + b1)  [N,256] bf16 (32 lanes/node, 16B loads)
    aggregate_bf16<32><<<(N + 7) / 8, 256, 0, stream>>>(Yl, Yr, b1, rowptr, adj, h1, N);

    // layer 2: [zl|zr] = h1 @ Wc2^T   ([N,128] each)
    gemm_wide<false><<<dim3(1, gm), 512, 0, stream>>>(
        (const float*)nullptr, h1, Wc2, zl, zr, N, 256, 256, 128);
    // h2  [N,128] bf16 (reuse Yl; 16 lanes/node)
    ushort* h2 = Yl;
    aggregate_bf16<16><<<(N + 15) / 16, 256, 0, stream>>>(zl, zr, b2, rowptr, adj, h2, N);

    // params p = h2 @ Wp^T + bp -> P [N,32] fp32 (8 lanes/node)
    params_kernel<<<(N + 31) / 32, 256, 0, stream>>>(h2, Wp, bp, Pp, N);
    // Cayley -> out [N,8,8] fp32
    cayley_kernel<<<(N + 255) / 256, 256, 0, stream>>>(Pp, out, N);
}